// Round 2
// baseline (689.393 us; speedup 1.0000x reference)
//
#include <hip/hip_runtime.h>
#include <hip/hip_bf16.h>
#include <math.h>

#define B_    4
#define T_    4096
#define E_    768
#define H_    6
#define D_    64
#define HD_   384
#define G_    1024
#define RATIO_ 4
#define TOPK_ 8

// ---------------------------------------------------------------------------
// 64x64-tile f32 GEMM, C[M,N] = A[M,K] @ B[K,N], all row-major.
// 256 threads, each computes 4x4. K-step 16. A staged transposed in LDS so the
// inner loop is 2x ds_read_b128 + 16 v_fma per kk.
// ---------------------------------------------------------------------------
__global__ __launch_bounds__(256) void gemm_nn_f32(
    const float* __restrict__ A, const float* __restrict__ B, float* __restrict__ C,
    int M, int N, int K, float scale)
{
  __shared__ float As[16][68];   // [k][m], padded
  __shared__ float Bs[16][68];   // [k][n], padded
  const int tid = threadIdx.x;
  const int tx = tid & 15, ty = tid >> 4;
  const int m0 = blockIdx.x * 64, n0 = blockIdx.y * 64;
  const int ar = tid >> 2, ac = (tid & 3) << 2;   // A tile: row 0..63, col 0..15 (x4)
  const int br = tid >> 4, bc = (tid & 15) << 2;  // B tile: row 0..15, col 0..63 (x4)
  float acc[4][4] = {};
  for (int k0 = 0; k0 < K; k0 += 16) {
    float4 av = *reinterpret_cast<const float4*>(&A[(size_t)(m0 + ar) * K + k0 + ac]);
    As[ac + 0][ar] = av.x; As[ac + 1][ar] = av.y;
    As[ac + 2][ar] = av.z; As[ac + 3][ar] = av.w;
    float4 bv = *reinterpret_cast<const float4*>(&B[(size_t)(k0 + br) * N + n0 + bc]);
    *reinterpret_cast<float4*>(&Bs[br][bc]) = bv;
    __syncthreads();
#pragma unroll
    for (int kk = 0; kk < 16; ++kk) {
      float4 a = *reinterpret_cast<const float4*>(&As[kk][ty << 2]);
      float4 b = *reinterpret_cast<const float4*>(&Bs[kk][tx << 2]);
      float aa[4] = {a.x, a.y, a.z, a.w};
      float bb[4] = {b.x, b.y, b.z, b.w};
#pragma unroll
      for (int i = 0; i < 4; ++i)
#pragma unroll
        for (int j = 0; j < 4; ++j) acc[i][j] = fmaf(aa[i], bb[j], acc[i][j]);
    }
    __syncthreads();
  }
#pragma unroll
  for (int i = 0; i < 4; ++i) {
    float4 o = make_float4(acc[i][0] * scale, acc[i][1] * scale,
                           acc[i][2] * scale, acc[i][3] * scale);
    *reinterpret_cast<float4*>(&C[(size_t)(m0 + (ty << 2) + i) * N + n0 + (tx << 2)]) = o;
  }
}

// ---------------------------------------------------------------------------
// Batched NT GEMM: C[z][M,N] = A[z][M,K] @ B[z][N,K]^T  (scores)
// ---------------------------------------------------------------------------
__global__ __launch_bounds__(256) void gemm_nt_f32(
    const float* __restrict__ A, const float* __restrict__ B, float* __restrict__ C,
    int M, int N, int K, float scale, size_t sA, size_t sB, size_t sC)
{
  __shared__ float As[16][68];   // [k][m]
  __shared__ float Bs[16][68];   // [k][n]
  const float* Ab = A + sA * blockIdx.z;
  const float* Bb = B + sB * blockIdx.z;
  float* Cb = C + sC * blockIdx.z;
  const int tid = threadIdx.x;
  const int tx = tid & 15, ty = tid >> 4;
  const int m0 = blockIdx.x * 64, n0 = blockIdx.y * 64;
  const int ar = tid >> 2, ac = (tid & 3) << 2;   // also used for B (rows of B = n)
  float acc[4][4] = {};
  for (int k0 = 0; k0 < K; k0 += 16) {
    float4 av = *reinterpret_cast<const float4*>(&Ab[(size_t)(m0 + ar) * K + k0 + ac]);
    As[ac + 0][ar] = av.x; As[ac + 1][ar] = av.y;
    As[ac + 2][ar] = av.z; As[ac + 3][ar] = av.w;
    float4 bv = *reinterpret_cast<const float4*>(&Bb[(size_t)(n0 + ar) * K + k0 + ac]);
    Bs[ac + 0][ar] = bv.x; Bs[ac + 1][ar] = bv.y;
    Bs[ac + 2][ar] = bv.z; Bs[ac + 3][ar] = bv.w;
    __syncthreads();
#pragma unroll
    for (int kk = 0; kk < 16; ++kk) {
      float4 a = *reinterpret_cast<const float4*>(&As[kk][ty << 2]);
      float4 b = *reinterpret_cast<const float4*>(&Bs[kk][tx << 2]);
      float aa[4] = {a.x, a.y, a.z, a.w};
      float bb[4] = {b.x, b.y, b.z, b.w};
#pragma unroll
      for (int i = 0; i < 4; ++i)
#pragma unroll
        for (int j = 0; j < 4; ++j) acc[i][j] = fmaf(aa[i], bb[j], acc[i][j]);
    }
    __syncthreads();
  }
#pragma unroll
  for (int i = 0; i < 4; ++i) {
    float4 o = make_float4(acc[i][0] * scale, acc[i][1] * scale,
                           acc[i][2] * scale, acc[i][3] * scale);
    *reinterpret_cast<float4*>(&Cb[(size_t)(m0 + (ty << 2) + i) * N + n0 + (tx << 2)]) = o;
  }
}

// ---------------------------------------------------------------------------
// In-place rmsnorm over rows of 64 (one wave per row; D_ == wave width)
// ---------------------------------------------------------------------------
__global__ __launch_bounds__(256) void rmsnorm_rows(float* __restrict__ x, int nrows)
{
  int row = (blockIdx.x * 256 + threadIdx.x) >> 6;
  int lane = threadIdx.x & 63;
  if (row >= nrows) return;
  float v = x[(size_t)row * 64 + lane];
  float ss = v * v;
#pragma unroll
  for (int off = 32; off; off >>= 1) ss += __shfl_xor(ss, off, 64);
  float sc = rsqrtf(ss * (1.0f / 64.0f) + 1e-6f);
  x[(size_t)row * 64 + lane] = v * sc;
}

// ---------------------------------------------------------------------------
// Gated pooling over ratio-groups + rmsnorm.  Block = one (b,g), 384 threads
// = 6 waves = 6 heads; lane = dim within head.
// ---------------------------------------------------------------------------
__global__ __launch_bounds__(384) void compress_kernel(
    const float* __restrict__ kproj, const float* __restrict__ gproj,
    const float* __restrict__ ape, float* __restrict__ keys)
{
  const int bg = blockIdx.x;            // b*G + g
  const int col = threadIdx.x;          // 0..383 = h*64+d
  const size_t base = (size_t)bg * (RATIO_ * HD_) + col;
  float kv[RATIO_], gv[RATIO_];
#pragma unroll
  for (int r = 0; r < RATIO_; ++r) {
    kv[r] = kproj[base + r * HD_];
    gv[r] = gproj[base + r * HD_] + ape[r * HD_ + col];
  }
  float mx = fmaxf(fmaxf(gv[0], gv[1]), fmaxf(gv[2], gv[3]));
  float e[RATIO_], s = 0.f;
#pragma unroll
  for (int r = 0; r < RATIO_; ++r) { e[r] = expf(gv[r] - mx); s += e[r]; }
  float inv = 1.0f / s;
  float key = 0.f;
#pragma unroll
  for (int r = 0; r < RATIO_; ++r) key = fmaf(kv[r], e[r] * inv, key);
  float ss = key * key;
#pragma unroll
  for (int off = 32; off; off >>= 1) ss += __shfl_xor(ss, off, 64);
  float sc = rsqrtf(ss * (1.0f / D_) + 1e-6f);
  keys[(size_t)bg * HD_ + col] = key * sc;
}

// ---------------------------------------------------------------------------
// Per-row causal top-8 -> overwrite scores row with 0/1 INT mask (in place).
// Tie-break: larger value, then smaller index (matches jax.lax.top_k).
// ---------------------------------------------------------------------------
__global__ __launch_bounds__(256) void topk_kernel(float* __restrict__ scores)
{
  const int t = blockIdx.x, b = blockIdx.y;
  __shared__ float s[G_];
  __shared__ float wv[4];
  __shared__ int wi[4];
  float* row = scores + ((size_t)b * T_ + t) * G_;
  const int tid = threadIdx.x;
  const int gmax = (t + 1) >> 2;     // #groups with group_end <= t
  float4 v = *reinterpret_cast<const float4*>(&row[tid << 2]);
  float vals[4] = {v.x, v.y, v.z, v.w};
#pragma unroll
  for (int j = 0; j < 4; ++j) {
    int g = (tid << 2) + j;
    s[g] = (g < gmax) ? vals[j] : -INFINITY;
  }
  __syncthreads();
  const int nsel = gmax < TOPK_ ? gmax : TOPK_;
  for (int it = 0; it < nsel; ++it) {
    float bv = -INFINITY; int bi = G_;
#pragma unroll
    for (int j = 0; j < 4; ++j) {
      int g = (tid << 2) + j;
      float x = s[g];
      if (x > bv) { bv = x; bi = g; }   // ascending scan + strict > keeps lowest idx
    }
#pragma unroll
    for (int off = 32; off; off >>= 1) {
      float ov = __shfl_xor(bv, off, 64);
      int oi = __shfl_xor(bi, off, 64);
      if (ov > bv || (ov == bv && oi < bi)) { bv = ov; bi = oi; }
    }
    if ((tid & 63) == 0) { wv[tid >> 6] = bv; wi[tid >> 6] = bi; }
    __syncthreads();
    if (tid == 0) {
      float fv = wv[0]; int fi = wi[0];
#pragma unroll
      for (int w = 1; w < 4; ++w)
        if (wv[w] > fv || (wv[w] == fv && wi[w] < fi)) { fv = wv[w]; fi = wi[w]; }
      s[fi] = -INFINITY;   // mark selected
    }
    __syncthreads();
  }
  // write INT32 0/1 mask (harness reads d_out as int32)
  int o[4];
#pragma unroll
  for (int j = 0; j < 4; ++j) {
    int g = (tid << 2) + j;
    o[j] = (g < gmax && s[g] == -INFINITY) ? 1 : 0;
  }
  int4* orow = reinterpret_cast<int4*>(row);
  orow[tid] = make_int4(o[0], o[1], o[2], o[3]);
}

__global__ __launch_bounds__(256) void write_ends(int* __restrict__ out)
{
  int g = blockIdx.x * 256 + threadIdx.x;
  if (g < G_) {
    int e = g * RATIO_ + RATIO_ - 1;
    out[g] = (e < T_ - 1 ? e : T_ - 1);
  }
}

extern "C" void kernel_launch(void* const* d_in, const int* in_sizes, int n_in,
                              void* d_out, int out_size, void* d_ws, size_t ws_size,
                              hipStream_t stream)
{
  const float* x   = (const float*)d_in[0];
  const float* wq  = (const float*)d_in[1];
  const float* wk  = (const float*)d_in[2];
  const float* wg  = (const float*)d_in[3];
  const float* ape = (const float*)d_in[4];
  float* out = (float*)d_out;

  // workspace: q [B,T,384] f32, keys [B,G,384] f32  (~31.5 MB)
  float* q    = (float*)d_ws;
  float* keys = q + (size_t)B_ * T_ * HD_;

  // d_out used as scratch for k/gate projections (overwritten by scores later)
  float* kproj = out;
  float* gproj = out + (size_t)B_ * T_ * HD_;

  dim3 blk(256);

  // k / gate projections -> d_out scratch
  gemm_nn_f32<<<dim3(B_ * T_ / 64, HD_ / 64, 1), blk, 0, stream>>>(
      x, wk, kproj, B_ * T_, HD_, E_, 1.0f);
  gemm_nn_f32<<<dim3(B_ * T_ / 64, HD_ / 64, 1), blk, 0, stream>>>(
      x, wg, gproj, B_ * T_, HD_, E_, 1.0f);
  // gated pooling + rmsnorm -> keys (ws)
  compress_kernel<<<dim3(B_ * G_), dim3(384), 0, stream>>>(kproj, gproj, ape, keys);

  // q projection + rmsnorm -> ws
  gemm_nn_f32<<<dim3(B_ * T_ / 64, HD_ / 64, 1), blk, 0, stream>>>(
      x, wq, q, B_ * T_, HD_, E_, 1.0f);
  rmsnorm_rows<<<dim3(B_ * T_ * H_ / 4), blk, 0, stream>>>(q, B_ * T_ * H_);

  // scores = q @ keys^T * (D^-0.5 / H)  -> d_out (full overwrite of scratch)
  gemm_nt_f32<<<dim3(T_ / 64, G_ / 64, B_), blk, 0, stream>>>(
      q, keys, out, T_, G_, HD_, 0.125f / 6.0f,
      (size_t)T_ * HD_, (size_t)G_ * HD_, (size_t)T_ * G_);

  // causal top-8 -> int mask (in place on d_out)
  topk_kernel<<<dim3(T_, B_), blk, 0, stream>>>(out);

  // group_ends as int32 at tail of d_out
  write_ends<<<dim3((G_ + 255) / 256), blk, 0, stream>>>(
      (int*)out + (size_t)B_ * T_ * G_);
}

// Round 3
// 217.550 us; speedup vs baseline: 3.1689x; 3.1689x over previous
//
#include <hip/hip_runtime.h>
#include <hip/hip_bf16.h>
#include <math.h>

#define B_    4
#define T_    4096
#define E_    768
#define H_    6
#define D_    64
#define HD_   384
#define G_    1024
#define RATIO_ 4
#define TOPK_ 8
#define MT_   (B_*T_)   // 16384 rows total

typedef __attribute__((ext_vector_type(8))) short short8;
typedef __attribute__((ext_vector_type(4))) float f32x4;
typedef __hip_bfloat16 bf16;

// async global->LDS, 16B per lane (dest must be wave-uniform base + lane*16)
#define GLD16(g, l) __builtin_amdgcn_global_load_lds( \
    (const __attribute__((address_space(1))) void*)(g), \
    (__attribute__((address_space(3))) void*)(l), 16, 0, 0)

static __device__ __forceinline__ unsigned short f2bf(float f) {
  bf16 h = __float2bfloat16(f);
  return __builtin_bit_cast(unsigned short, h);
}

// ---------------------------------------------------------------------------
// x f32 -> bf16 (8 elems/thread)
// ---------------------------------------------------------------------------
__global__ __launch_bounds__(256) void cvt_x_kernel(
    const float* __restrict__ in, bf16* __restrict__ out)
{
  size_t i = (size_t)blockIdx.x * 256 + threadIdx.x;
  const float4* p = reinterpret_cast<const float4*>(in) + i * 2;
  float4 v0 = p[0], v1 = p[1];
  float f[8] = {v0.x, v0.y, v0.z, v0.w, v1.x, v1.y, v1.z, v1.w};
  union { unsigned short u[8]; short8 v; } r;
#pragma unroll
  for (int k = 0; k < 8; ++k) r.u[k] = f2bf(f[k]);
  *reinterpret_cast<short8*>(out + i * 8) = r.v;
}

// ---------------------------------------------------------------------------
// transpose+convert weights: w [768][384] f32 -> wT [384][768] bf16 (x3)
// ---------------------------------------------------------------------------
__global__ __launch_bounds__(256) void cvt_w_t(
    const float* __restrict__ wq, const float* __restrict__ wk,
    const float* __restrict__ wg, bf16* __restrict__ outbase)
{
  const float* src = blockIdx.z == 0 ? wq : (blockIdx.z == 1 ? wk : wg);
  bf16* dst = outbase + (size_t)blockIdx.z * HD_ * E_;
  __shared__ float t[32][33];
  int r = threadIdx.x >> 5, c = threadIdx.x & 31;
  int k0 = blockIdx.x * 32, n0 = blockIdx.y * 32;
#pragma unroll
  for (int i = 0; i < 4; ++i)
    t[r + i * 8][c] = src[(size_t)(k0 + r + i * 8) * HD_ + n0 + c];
  __syncthreads();
#pragma unroll
  for (int i = 0; i < 4; ++i)
    dst[(size_t)(n0 + r + i * 8) * E_ + k0 + c] = __float2bfloat16(t[c][r + i * 8]);
}

// ---------------------------------------------------------------------------
// Fused k/gate projection + gated pooling + rmsnorm -> keys bf16 [B*G][384].
// NT MFMA: A = x_bf16 [MT][768], B = wT [384][768]. 128x128 tile, BK=32,
// 4 waves (2x2), each wave 64x64 via 4x4 frags of 16x16x32.
// Epilogue: group of 4 rows == regs j=0..3 of one fragment (lane-local softmax).
// ---------------------------------------------------------------------------
__global__ __launch_bounds__(256) void gemm_kg_mfma(
    const bf16* __restrict__ X, const bf16* __restrict__ WkT,
    const bf16* __restrict__ WgT, const float* __restrict__ ape,
    bf16* __restrict__ keys)
{
  __shared__ bf16 As[128 * 32], BsK[128 * 32], BsG[128 * 32];
  const int tid = threadIdx.x;
  const int lane = tid & 63, wv = tid >> 6;
  const int wm = wv >> 1, wn = wv & 1;
  const int ll = lane & 15, lh = lane >> 4;
  const int m0 = blockIdx.x * 128, n0 = blockIdx.y * 128;
  const int sr = tid >> 2, sc = (tid & 3) << 3;
  f32x4 accK[4][4], accG[4][4];
#pragma unroll
  for (int m = 0; m < 4; ++m)
#pragma unroll
    for (int n = 0; n < 4; ++n) {
      accK[m][n] = (f32x4){0.f, 0.f, 0.f, 0.f};
      accG[m][n] = (f32x4){0.f, 0.f, 0.f, 0.f};
    }
  for (int k0 = 0; k0 < E_; k0 += 32) {
    GLD16(X   + (size_t)(m0 + sr) * E_      + k0 + sc, (char*)As  + tid * 16);
    GLD16(X   + (size_t)(m0 + 64 + sr) * E_ + k0 + sc, (char*)As  + tid * 16 + 4096);
    GLD16(WkT + (size_t)(n0 + sr) * E_      + k0 + sc, (char*)BsK + tid * 16);
    GLD16(WkT + (size_t)(n0 + 64 + sr) * E_ + k0 + sc, (char*)BsK + tid * 16 + 4096);
    GLD16(WgT + (size_t)(n0 + sr) * E_      + k0 + sc, (char*)BsG + tid * 16);
    GLD16(WgT + (size_t)(n0 + 64 + sr) * E_ + k0 + sc, (char*)BsG + tid * 16 + 4096);
    __syncthreads();
    short8 a[4], bk[4], bg[4];
#pragma unroll
    for (int m = 0; m < 4; ++m)
      a[m] = *reinterpret_cast<const short8*>(&As[(wm * 64 + m * 16 + ll) * 32 + lh * 8]);
#pragma unroll
    for (int n = 0; n < 4; ++n) {
      bk[n] = *reinterpret_cast<const short8*>(&BsK[(wn * 64 + n * 16 + ll) * 32 + lh * 8]);
      bg[n] = *reinterpret_cast<const short8*>(&BsG[(wn * 64 + n * 16 + ll) * 32 + lh * 8]);
    }
#pragma unroll
    for (int m = 0; m < 4; ++m)
#pragma unroll
      for (int n = 0; n < 4; ++n) {
        accK[m][n] = __builtin_amdgcn_mfma_f32_16x16x32_bf16(a[m], bk[n], accK[m][n], 0, 0, 0);
        accG[m][n] = __builtin_amdgcn_mfma_f32_16x16x32_bf16(a[m], bg[n], accG[m][n], 0, 0, 0);
      }
    __syncthreads();
  }
  // epilogue: per-column softmax over the 4 group members (regs j=0..3),
  // pooled key, then rmsnorm over the wave's 64-col head.
  float apev[4][4];
#pragma unroll
  for (int n = 0; n < 4; ++n) {
    int col = n0 + wn * 64 + n * 16 + ll;
#pragma unroll
    for (int j = 0; j < 4; ++j) apev[n][j] = ape[j * HD_ + col];
  }
#pragma unroll
  for (int m = 0; m < 4; ++m) {
    float pooled[4];
#pragma unroll
    for (int n = 0; n < 4; ++n) {
      float g0 = accG[m][n][0] + apev[n][0], g1 = accG[m][n][1] + apev[n][1];
      float g2 = accG[m][n][2] + apev[n][2], g3 = accG[m][n][3] + apev[n][3];
      float mx = fmaxf(fmaxf(g0, g1), fmaxf(g2, g3));
      float e0 = expf(g0 - mx), e1 = expf(g1 - mx);
      float e2 = expf(g2 - mx), e3 = expf(g3 - mx);
      float inv = 1.0f / (e0 + e1 + e2 + e3);
      pooled[n] = (accK[m][n][0] * e0 + accK[m][n][1] * e1 +
                   accK[m][n][2] * e2 + accK[m][n][3] * e3) * inv;
    }
    float ss = pooled[0] * pooled[0] + pooled[1] * pooled[1] +
               pooled[2] * pooled[2] + pooled[3] * pooled[3];
    ss += __shfl_xor(ss, 1, 64); ss += __shfl_xor(ss, 2, 64);
    ss += __shfl_xor(ss, 4, 64); ss += __shfl_xor(ss, 8, 64);
    float scl = rsqrtf(ss * (1.0f / D_) + 1e-6f);
    int prow = (m0 >> 2) + wm * 16 + m * 4 + lh;
#pragma unroll
    for (int n = 0; n < 4; ++n)
      keys[(size_t)prow * HD_ + n0 + wn * 64 + n * 16 + ll] =
          __float2bfloat16(pooled[n] * scl);
  }
}

// ---------------------------------------------------------------------------
// q projection + per-head rmsnorm -> q bf16 [MT][384]
// ---------------------------------------------------------------------------
__global__ __launch_bounds__(256) void gemm_q_mfma(
    const bf16* __restrict__ X, const bf16* __restrict__ WqT,
    bf16* __restrict__ Q)
{
  __shared__ bf16 As[128 * 32], Bs[128 * 32];
  const int tid = threadIdx.x;
  const int lane = tid & 63, wv = tid >> 6;
  const int wm = wv >> 1, wn = wv & 1;
  const int ll = lane & 15, lh = lane >> 4;
  const int m0 = blockIdx.x * 128, n0 = blockIdx.y * 128;
  const int sr = tid >> 2, sc = (tid & 3) << 3;
  f32x4 acc[4][4];
#pragma unroll
  for (int m = 0; m < 4; ++m)
#pragma unroll
    for (int n = 0; n < 4; ++n) acc[m][n] = (f32x4){0.f, 0.f, 0.f, 0.f};
  for (int k0 = 0; k0 < E_; k0 += 32) {
    GLD16(X   + (size_t)(m0 + sr) * E_      + k0 + sc, (char*)As + tid * 16);
    GLD16(X   + (size_t)(m0 + 64 + sr) * E_ + k0 + sc, (char*)As + tid * 16 + 4096);
    GLD16(WqT + (size_t)(n0 + sr) * E_      + k0 + sc, (char*)Bs + tid * 16);
    GLD16(WqT + (size_t)(n0 + 64 + sr) * E_ + k0 + sc, (char*)Bs + tid * 16 + 4096);
    __syncthreads();
    short8 a[4], b[4];
#pragma unroll
    for (int m = 0; m < 4; ++m)
      a[m] = *reinterpret_cast<const short8*>(&As[(wm * 64 + m * 16 + ll) * 32 + lh * 8]);
#pragma unroll
    for (int n = 0; n < 4; ++n)
      b[n] = *reinterpret_cast<const short8*>(&Bs[(wn * 64 + n * 16 + ll) * 32 + lh * 8]);
#pragma unroll
    for (int m = 0; m < 4; ++m)
#pragma unroll
      for (int n = 0; n < 4; ++n)
        acc[m][n] = __builtin_amdgcn_mfma_f32_16x16x32_bf16(a[m], b[n], acc[m][n], 0, 0, 0);
    __syncthreads();
  }
  // rmsnorm per output row over the wave's 64-col head, then bf16 store
#pragma unroll
  for (int m = 0; m < 4; ++m)
#pragma unroll
    for (int j = 0; j < 4; ++j) {
      float ss = 0.f;
#pragma unroll
      for (int n = 0; n < 4; ++n) ss += acc[m][n][j] * acc[m][n][j];
      ss += __shfl_xor(ss, 1, 64); ss += __shfl_xor(ss, 2, 64);
      ss += __shfl_xor(ss, 4, 64); ss += __shfl_xor(ss, 8, 64);
      float scl = rsqrtf(ss * (1.0f / D_) + 1e-6f);
      int row = m0 + wm * 64 + m * 16 + lh * 4 + j;
#pragma unroll
      for (int n = 0; n < 4; ++n)
        Q[(size_t)row * HD_ + n0 + wn * 64 + n * 16 + ll] =
            __float2bfloat16(acc[m][n][j] * scl);
    }
}

// ---------------------------------------------------------------------------
// Batched score GEMM: scores[z] = q[z] @ keys[z]^T * (D^-0.5 / H) -> f32
// ---------------------------------------------------------------------------
__global__ __launch_bounds__(256) void gemm_score_mfma(
    const bf16* __restrict__ Qall, const bf16* __restrict__ Kall,
    float* __restrict__ Call)
{
  __shared__ bf16 As[128 * 32], Bs[128 * 32];
  const bf16* Q = Qall + (size_t)blockIdx.z * T_ * HD_;
  const bf16* Kk = Kall + (size_t)blockIdx.z * G_ * HD_;
  float* C = Call + (size_t)blockIdx.z * T_ * G_;
  const int tid = threadIdx.x;
  const int lane = tid & 63, wv = tid >> 6;
  const int wm = wv >> 1, wn = wv & 1;
  const int ll = lane & 15, lh = lane >> 4;
  const int m0 = blockIdx.x * 128, n0 = blockIdx.y * 128;
  const int sr = tid >> 2, sc = (tid & 3) << 3;
  f32x4 acc[4][4];
#pragma unroll
  for (int m = 0; m < 4; ++m)
#pragma unroll
    for (int n = 0; n < 4; ++n) acc[m][n] = (f32x4){0.f, 0.f, 0.f, 0.f};
  for (int k0 = 0; k0 < HD_; k0 += 32) {
    GLD16(Q  + (size_t)(m0 + sr) * HD_      + k0 + sc, (char*)As + tid * 16);
    GLD16(Q  + (size_t)(m0 + 64 + sr) * HD_ + k0 + sc, (char*)As + tid * 16 + 4096);
    GLD16(Kk + (size_t)(n0 + sr) * HD_      + k0 + sc, (char*)Bs + tid * 16);
    GLD16(Kk + (size_t)(n0 + 64 + sr) * HD_ + k0 + sc, (char*)Bs + tid * 16 + 4096);
    __syncthreads();
    short8 a[4], b[4];
#pragma unroll
    for (int m = 0; m < 4; ++m)
      a[m] = *reinterpret_cast<const short8*>(&As[(wm * 64 + m * 16 + ll) * 32 + lh * 8]);
#pragma unroll
    for (int n = 0; n < 4; ++n)
      b[n] = *reinterpret_cast<const short8*>(&Bs[(wn * 64 + n * 16 + ll) * 32 + lh * 8]);
#pragma unroll
    for (int m = 0; m < 4; ++m)
#pragma unroll
      for (int n = 0; n < 4; ++n)
        acc[m][n] = __builtin_amdgcn_mfma_f32_16x16x32_bf16(a[m], b[n], acc[m][n], 0, 0, 0);
    __syncthreads();
  }
  const float scale = 0.125f / 6.0f;
#pragma unroll
  for (int m = 0; m < 4; ++m)
#pragma unroll
    for (int j = 0; j < 4; ++j) {
      int row = m0 + wm * 64 + m * 16 + lh * 4 + j;
#pragma unroll
      for (int n = 0; n < 4; ++n)
        C[(size_t)row * G_ + n0 + wn * 64 + n * 16 + ll] = acc[m][n][j] * scale;
    }
}

// ---------------------------------------------------------------------------
// Per-row causal top-8 -> overwrite scores row with 0/1 INT mask (in place).
// ---------------------------------------------------------------------------
__global__ __launch_bounds__(256) void topk_kernel(float* __restrict__ scores)
{
  const int t = blockIdx.x, b = blockIdx.y;
  __shared__ float s[G_];
  __shared__ float wvv[4];
  __shared__ int wii[4];
  float* row = scores + ((size_t)b * T_ + t) * G_;
  const int tid = threadIdx.x;
  const int gmax = (t + 1) >> 2;
  float4 v = *reinterpret_cast<const float4*>(&row[tid << 2]);
  float vals[4] = {v.x, v.y, v.z, v.w};
#pragma unroll
  for (int j = 0; j < 4; ++j) {
    int g = (tid << 2) + j;
    s[g] = (g < gmax) ? vals[j] : -INFINITY;
  }
  __syncthreads();
  const int nsel = gmax < TOPK_ ? gmax : TOPK_;
  for (int it = 0; it < nsel; ++it) {
    float bv = -INFINITY; int bi = G_;
#pragma unroll
    for (int j = 0; j < 4; ++j) {
      int g = (tid << 2) + j;
      float x = s[g];
      if (x > bv) { bv = x; bi = g; }
    }
#pragma unroll
    for (int off = 32; off; off >>= 1) {
      float ov = __shfl_xor(bv, off, 64);
      int oi = __shfl_xor(bi, off, 64);
      if (ov > bv || (ov == bv && oi < bi)) { bv = ov; bi = oi; }
    }
    if ((tid & 63) == 0) { wvv[tid >> 6] = bv; wii[tid >> 6] = bi; }
    __syncthreads();
    if (tid == 0) {
      float fv = wvv[0]; int fi = wii[0];
#pragma unroll
      for (int w = 1; w < 4; ++w)
        if (wvv[w] > fv || (wvv[w] == fv && wii[w] < fi)) { fv = wvv[w]; fi = wii[w]; }
      s[fi] = -INFINITY;
    }
    __syncthreads();
  }
  int o[4];
#pragma unroll
  for (int j = 0; j < 4; ++j) {
    int g = (tid << 2) + j;
    o[j] = (g < gmax && s[g] == -INFINITY) ? 1 : 0;
  }
  reinterpret_cast<int4*>(row)[tid] = make_int4(o[0], o[1], o[2], o[3]);
}

__global__ __launch_bounds__(256) void write_ends(int* __restrict__ out)
{
  int g = blockIdx.x * 256 + threadIdx.x;
  if (g < G_) {
    int e = g * RATIO_ + RATIO_ - 1;
    out[g] = (e < T_ - 1 ? e : T_ - 1);
  }
}

extern "C" void kernel_launch(void* const* d_in, const int* in_sizes, int n_in,
                              void* d_out, int out_size, void* d_ws, size_t ws_size,
                              hipStream_t stream)
{
  const float* x   = (const float*)d_in[0];
  const float* wq  = (const float*)d_in[1];
  const float* wk  = (const float*)d_in[2];
  const float* wg  = (const float*)d_in[3];
  const float* ape = (const float*)d_in[4];

  // ws layout (bf16): wT[3][384][768] | q[16384][384] | keys[4096][384]
  bf16* wT   = (bf16*)d_ws;
  bf16* qb   = wT + 3 * (size_t)HD_ * E_;
  bf16* keys = qb + (size_t)MT_ * HD_;

  // x_bf16 staged in d_out (dead before scores overwrite it)
  bf16* xb = (bf16*)d_out;

  cvt_x_kernel<<<dim3(MT_ * E_ / 8 / 256), dim3(256), 0, stream>>>(x, xb);
  cvt_w_t<<<dim3(E_ / 32, HD_ / 32, 3), dim3(256), 0, stream>>>(wq, wk, wg, wT);

  gemm_kg_mfma<<<dim3(MT_ / 128, HD_ / 128), dim3(256), 0, stream>>>(
      xb, wT + (size_t)HD_ * E_, wT + 2 * (size_t)HD_ * E_, ape, keys);
  gemm_q_mfma<<<dim3(MT_ / 128, HD_ / 128), dim3(256), 0, stream>>>(xb, wT, qb);

  gemm_score_mfma<<<dim3(T_ / 128, G_ / 128, B_), dim3(256), 0, stream>>>(
      qb, keys, (float*)d_out);

  topk_kernel<<<dim3(T_, B_), dim3(256), 0, stream>>>((float*)d_out);
  write_ends<<<dim3((G_ + 255) / 256), dim3(256), 0, stream>>>(
      (int*)d_out + (size_t)B_ * T_ * G_);
}

// Round 4
// 158.777 us; speedup vs baseline: 4.3419x; 1.3702x over previous
//
#include <hip/hip_runtime.h>
#include <hip/hip_bf16.h>
#include <math.h>

#define B_    4
#define T_    4096
#define E_    768
#define H_    6
#define D_    64
#define HD_   384
#define G_    1024
#define RATIO_ 4
#define TOPK_ 8
#define MT_   (B_*T_)   // 16384 rows total

typedef __attribute__((ext_vector_type(8))) short short8;
typedef __attribute__((ext_vector_type(4))) float f32x4;
typedef __hip_bfloat16 bf16;

// async global->LDS, 16B per lane (dest must be wave-uniform base + lane*16)
#define GLD16(g, l) __builtin_amdgcn_global_load_lds( \
    (const __attribute__((address_space(1))) void*)(g), \
    (__attribute__((address_space(3))) void*)(l), 16, 0, 0)

static __device__ __forceinline__ unsigned short f2bf(float f) {
  bf16 h = __float2bfloat16(f);
  return __builtin_bit_cast(unsigned short, h);
}

// ---------------------------------------------------------------------------
// x f32 -> bf16 (8 elems/thread)
// ---------------------------------------------------------------------------
__global__ __launch_bounds__(256) void cvt_x_kernel(
    const float* __restrict__ in, bf16* __restrict__ out)
{
  size_t i = (size_t)blockIdx.x * 256 + threadIdx.x;
  const float4* p = reinterpret_cast<const float4*>(in) + i * 2;
  float4 v0 = p[0], v1 = p[1];
  float f[8] = {v0.x, v0.y, v0.z, v0.w, v1.x, v1.y, v1.z, v1.w};
  union { unsigned short u[8]; short8 v; } r;
#pragma unroll
  for (int k = 0; k < 8; ++k) r.u[k] = f2bf(f[k]);
  *reinterpret_cast<short8*>(out + i * 8) = r.v;
}

// ---------------------------------------------------------------------------
// transpose+convert weights: w [768][384] f32 -> wT [384][768] bf16 (x3)
// ---------------------------------------------------------------------------
__global__ __launch_bounds__(256) void cvt_w_t(
    const float* __restrict__ wq, const float* __restrict__ wk,
    const float* __restrict__ wg, bf16* __restrict__ outbase)
{
  const float* src = blockIdx.z == 0 ? wq : (blockIdx.z == 1 ? wk : wg);
  bf16* dst = outbase + (size_t)blockIdx.z * HD_ * E_;
  __shared__ float t[32][33];
  int r = threadIdx.x >> 5, c = threadIdx.x & 31;
  int k0 = blockIdx.x * 32, n0 = blockIdx.y * 32;
#pragma unroll
  for (int i = 0; i < 4; ++i)
    t[r + i * 8][c] = src[(size_t)(k0 + r + i * 8) * HD_ + n0 + c];
  __syncthreads();
#pragma unroll
  for (int i = 0; i < 4; ++i)
    dst[(size_t)(n0 + r + i * 8) * E_ + k0 + c] = __float2bfloat16(t[c][r + i * 8]);
}

// ---------------------------------------------------------------------------
// Fused k/gate projection + gated pooling + rmsnorm -> keys bf16 [B*G][384].
// ---------------------------------------------------------------------------
__global__ __launch_bounds__(256) void gemm_kg_mfma(
    const bf16* __restrict__ X, const bf16* __restrict__ WkT,
    const bf16* __restrict__ WgT, const float* __restrict__ ape,
    bf16* __restrict__ keys)
{
  __shared__ bf16 As[128 * 32], BsK[128 * 32], BsG[128 * 32];
  const int tid = threadIdx.x;
  const int lane = tid & 63, wv = tid >> 6;
  const int wm = wv >> 1, wn = wv & 1;
  const int ll = lane & 15, lh = lane >> 4;
  const int m0 = blockIdx.x * 128, n0 = blockIdx.y * 128;
  const int sr = tid >> 2, sc = (tid & 3) << 3;
  f32x4 accK[4][4], accG[4][4];
#pragma unroll
  for (int m = 0; m < 4; ++m)
#pragma unroll
    for (int n = 0; n < 4; ++n) {
      accK[m][n] = (f32x4){0.f, 0.f, 0.f, 0.f};
      accG[m][n] = (f32x4){0.f, 0.f, 0.f, 0.f};
    }
  for (int k0 = 0; k0 < E_; k0 += 32) {
    GLD16(X   + (size_t)(m0 + sr) * E_      + k0 + sc, (char*)As  + tid * 16);
    GLD16(X   + (size_t)(m0 + 64 + sr) * E_ + k0 + sc, (char*)As  + tid * 16 + 4096);
    GLD16(WkT + (size_t)(n0 + sr) * E_      + k0 + sc, (char*)BsK + tid * 16);
    GLD16(WkT + (size_t)(n0 + 64 + sr) * E_ + k0 + sc, (char*)BsK + tid * 16 + 4096);
    GLD16(WgT + (size_t)(n0 + sr) * E_      + k0 + sc, (char*)BsG + tid * 16);
    GLD16(WgT + (size_t)(n0 + 64 + sr) * E_ + k0 + sc, (char*)BsG + tid * 16 + 4096);
    __syncthreads();
    short8 a[4], bk[4], bg[4];
#pragma unroll
    for (int m = 0; m < 4; ++m)
      a[m] = *reinterpret_cast<const short8*>(&As[(wm * 64 + m * 16 + ll) * 32 + lh * 8]);
#pragma unroll
    for (int n = 0; n < 4; ++n) {
      bk[n] = *reinterpret_cast<const short8*>(&BsK[(wn * 64 + n * 16 + ll) * 32 + lh * 8]);
      bg[n] = *reinterpret_cast<const short8*>(&BsG[(wn * 64 + n * 16 + ll) * 32 + lh * 8]);
    }
#pragma unroll
    for (int m = 0; m < 4; ++m)
#pragma unroll
      for (int n = 0; n < 4; ++n) {
        accK[m][n] = __builtin_amdgcn_mfma_f32_16x16x32_bf16(a[m], bk[n], accK[m][n], 0, 0, 0);
        accG[m][n] = __builtin_amdgcn_mfma_f32_16x16x32_bf16(a[m], bg[n], accG[m][n], 0, 0, 0);
      }
    __syncthreads();
  }
  float apev[4][4];
#pragma unroll
  for (int n = 0; n < 4; ++n) {
    int col = n0 + wn * 64 + n * 16 + ll;
#pragma unroll
    for (int j = 0; j < 4; ++j) apev[n][j] = ape[j * HD_ + col];
  }
#pragma unroll
  for (int m = 0; m < 4; ++m) {
    float pooled[4];
#pragma unroll
    for (int n = 0; n < 4; ++n) {
      float g0 = accG[m][n][0] + apev[n][0], g1 = accG[m][n][1] + apev[n][1];
      float g2 = accG[m][n][2] + apev[n][2], g3 = accG[m][n][3] + apev[n][3];
      float mx = fmaxf(fmaxf(g0, g1), fmaxf(g2, g3));
      float e0 = expf(g0 - mx), e1 = expf(g1 - mx);
      float e2 = expf(g2 - mx), e3 = expf(g3 - mx);
      float inv = 1.0f / (e0 + e1 + e2 + e3);
      pooled[n] = (accK[m][n][0] * e0 + accK[m][n][1] * e1 +
                   accK[m][n][2] * e2 + accK[m][n][3] * e3) * inv;
    }
    float ss = pooled[0] * pooled[0] + pooled[1] * pooled[1] +
               pooled[2] * pooled[2] + pooled[3] * pooled[3];
    ss += __shfl_xor(ss, 1, 64); ss += __shfl_xor(ss, 2, 64);
    ss += __shfl_xor(ss, 4, 64); ss += __shfl_xor(ss, 8, 64);
    float scl = rsqrtf(ss * (1.0f / D_) + 1e-6f);
    int prow = (m0 >> 2) + wm * 16 + m * 4 + lh;
#pragma unroll
    for (int n = 0; n < 4; ++n)
      keys[(size_t)prow * HD_ + n0 + wn * 64 + n * 16 + ll] =
          __float2bfloat16(pooled[n] * scl);
  }
}

// ---------------------------------------------------------------------------
// q projection + per-head rmsnorm -> q bf16 [MT][384]
// ---------------------------------------------------------------------------
__global__ __launch_bounds__(256) void gemm_q_mfma(
    const bf16* __restrict__ X, const bf16* __restrict__ WqT,
    bf16* __restrict__ Q)
{
  __shared__ bf16 As[128 * 32], Bs[128 * 32];
  const int tid = threadIdx.x;
  const int lane = tid & 63, wv = tid >> 6;
  const int wm = wv >> 1, wn = wv & 1;
  const int ll = lane & 15, lh = lane >> 4;
  const int m0 = blockIdx.x * 128, n0 = blockIdx.y * 128;
  const int sr = tid >> 2, sc = (tid & 3) << 3;
  f32x4 acc[4][4];
#pragma unroll
  for (int m = 0; m < 4; ++m)
#pragma unroll
    for (int n = 0; n < 4; ++n) acc[m][n] = (f32x4){0.f, 0.f, 0.f, 0.f};
  for (int k0 = 0; k0 < E_; k0 += 32) {
    GLD16(X   + (size_t)(m0 + sr) * E_      + k0 + sc, (char*)As + tid * 16);
    GLD16(X   + (size_t)(m0 + 64 + sr) * E_ + k0 + sc, (char*)As + tid * 16 + 4096);
    GLD16(WqT + (size_t)(n0 + sr) * E_      + k0 + sc, (char*)Bs + tid * 16);
    GLD16(WqT + (size_t)(n0 + 64 + sr) * E_ + k0 + sc, (char*)Bs + tid * 16 + 4096);
    __syncthreads();
    short8 a[4], b[4];
#pragma unroll
    for (int m = 0; m < 4; ++m)
      a[m] = *reinterpret_cast<const short8*>(&As[(wm * 64 + m * 16 + ll) * 32 + lh * 8]);
#pragma unroll
    for (int n = 0; n < 4; ++n)
      b[n] = *reinterpret_cast<const short8*>(&Bs[(wn * 64 + n * 16 + ll) * 32 + lh * 8]);
#pragma unroll
    for (int m = 0; m < 4; ++m)
#pragma unroll
      for (int n = 0; n < 4; ++n)
        acc[m][n] = __builtin_amdgcn_mfma_f32_16x16x32_bf16(a[m], b[n], acc[m][n], 0, 0, 0);
    __syncthreads();
  }
#pragma unroll
  for (int m = 0; m < 4; ++m)
#pragma unroll
    for (int j = 0; j < 4; ++j) {
      float ss = 0.f;
#pragma unroll
      for (int n = 0; n < 4; ++n) ss += acc[m][n][j] * acc[m][n][j];
      ss += __shfl_xor(ss, 1, 64); ss += __shfl_xor(ss, 2, 64);
      ss += __shfl_xor(ss, 4, 64); ss += __shfl_xor(ss, 8, 64);
      float scl = rsqrtf(ss * (1.0f / D_) + 1e-6f);
      int row = m0 + wm * 64 + m * 16 + lh * 4 + j;
#pragma unroll
      for (int n = 0; n < 4; ++n)
        Q[(size_t)row * HD_ + n0 + wn * 64 + n * 16 + ll] =
            __float2bfloat16(acc[m][n][j] * scl);
    }
}

// ---------------------------------------------------------------------------
// Batched score GEMM: scores[z] = q[z] @ keys[z]^T * (D^-0.5 / H) -> f32
// Causal dead-block skip: columns g >= gmax(t) are never read by topk.
// ---------------------------------------------------------------------------
__global__ __launch_bounds__(256) void gemm_score_mfma(
    const bf16* __restrict__ Qall, const bf16* __restrict__ Kall,
    float* __restrict__ Call)
{
  const int m0 = blockIdx.x * 128, n0 = blockIdx.y * 128;
  if (4 * n0 >= m0 + 128) return;   // fully non-causal tile: topk never reads it
  __shared__ bf16 As[128 * 32], Bs[128 * 32];
  const bf16* Q = Qall + (size_t)blockIdx.z * T_ * HD_;
  const bf16* Kk = Kall + (size_t)blockIdx.z * G_ * HD_;
  float* C = Call + (size_t)blockIdx.z * T_ * G_;
  const int tid = threadIdx.x;
  const int lane = tid & 63, wv = tid >> 6;
  const int wm = wv >> 1, wn = wv & 1;
  const int ll = lane & 15, lh = lane >> 4;
  const int sr = tid >> 2, sc = (tid & 3) << 3;
  f32x4 acc[4][4];
#pragma unroll
  for (int m = 0; m < 4; ++m)
#pragma unroll
    for (int n = 0; n < 4; ++n) acc[m][n] = (f32x4){0.f, 0.f, 0.f, 0.f};
  for (int k0 = 0; k0 < HD_; k0 += 32) {
    GLD16(Q  + (size_t)(m0 + sr) * HD_      + k0 + sc, (char*)As + tid * 16);
    GLD16(Q  + (size_t)(m0 + 64 + sr) * HD_ + k0 + sc, (char*)As + tid * 16 + 4096);
    GLD16(Kk + (size_t)(n0 + sr) * HD_      + k0 + sc, (char*)Bs + tid * 16);
    GLD16(Kk + (size_t)(n0 + 64 + sr) * HD_ + k0 + sc, (char*)Bs + tid * 16 + 4096);
    __syncthreads();
    short8 a[4], b[4];
#pragma unroll
    for (int m = 0; m < 4; ++m)
      a[m] = *reinterpret_cast<const short8*>(&As[(wm * 64 + m * 16 + ll) * 32 + lh * 8]);
#pragma unroll
    for (int n = 0; n < 4; ++n)
      b[n] = *reinterpret_cast<const short8*>(&Bs[(wn * 64 + n * 16 + ll) * 32 + lh * 8]);
#pragma unroll
    for (int m = 0; m < 4; ++m)
#pragma unroll
      for (int n = 0; n < 4; ++n)
        acc[m][n] = __builtin_amdgcn_mfma_f32_16x16x32_bf16(a[m], b[n], acc[m][n], 0, 0, 0);
    __syncthreads();
  }
  const float scale = 0.125f / 6.0f;
#pragma unroll
  for (int m = 0; m < 4; ++m)
#pragma unroll
    for (int j = 0; j < 4; ++j) {
      int row = m0 + wm * 64 + m * 16 + lh * 4 + j;
#pragma unroll
      for (int n = 0; n < 4; ++n)
        C[(size_t)row * G_ + n0 + wn * 64 + n * 16 + ll] = acc[m][n][j] * scale;
    }
}

// ---------------------------------------------------------------------------
// Wave-per-row causal top-8: no LDS, no barriers. Lane holds 16 scores in
// registers; cached (max,idx) per lane; 6-step shfl_xor argmax reduce with
// index tie-break; winner lane clears slot + rescans. Mask written as int 0/1.
// ---------------------------------------------------------------------------
__global__ __launch_bounds__(256) void topk_kernel(float* __restrict__ scores)
{
  const int r = blockIdx.x * 4 + (threadIdx.x >> 6);
  const int lane = threadIdx.x & 63;
  const int t = r & (T_ - 1);
  const int gmax = (t + 1) >> 2;
  float* row = scores + (size_t)r * G_;
  const int base = lane << 4;
  const float4* p = reinterpret_cast<const float4*>(row + base);
  float4 x0 = p[0], x1 = p[1], x2 = p[2], x3 = p[3];
  float v[16] = {x0.x, x0.y, x0.z, x0.w, x1.x, x1.y, x1.z, x1.w,
                 x2.x, x2.y, x2.z, x2.w, x3.x, x3.y, x3.z, x3.w};
#pragma unroll
  for (int j = 0; j < 16; ++j)
    if (base + j >= gmax) v[j] = -INFINITY;
  float lv = v[0]; int li = 0;
#pragma unroll
  for (int j = 1; j < 16; ++j)
    if (v[j] > lv) { lv = v[j]; li = j; }
  unsigned sel = 0;
  const int nsel = gmax < TOPK_ ? gmax : TOPK_;
  for (int it = 0; it < nsel; ++it) {
    float bv = lv; int bi = base + li;
#pragma unroll
    for (int off = 1; off < 64; off <<= 1) {
      float ov = __shfl_xor(bv, off, 64);
      int oi = __shfl_xor(bi, off, 64);
      if (ov > bv || (ov == bv && oi < bi)) { bv = ov; bi = oi; }
    }
    if ((bi >> 4) == lane) {          // winner lane only
      sel |= 1u << (bi & 15);
      v[bi & 15] = -INFINITY;
      lv = v[0]; li = 0;
#pragma unroll
      for (int j = 1; j < 16; ++j)
        if (v[j] > lv) { lv = v[j]; li = j; }
    }
  }
  int4* q = reinterpret_cast<int4*>(row + base);
#pragma unroll
  for (int c = 0; c < 4; ++c)
    q[c] = make_int4((sel >> (4 * c)) & 1, (sel >> (4 * c + 1)) & 1,
                     (sel >> (4 * c + 2)) & 1, (sel >> (4 * c + 3)) & 1);
}

__global__ __launch_bounds__(256) void write_ends(int* __restrict__ out)
{
  int g = blockIdx.x * 256 + threadIdx.x;
  if (g < G_) {
    int e = g * RATIO_ + RATIO_ - 1;
    out[g] = (e < T_ - 1 ? e : T_ - 1);
  }
}

extern "C" void kernel_launch(void* const* d_in, const int* in_sizes, int n_in,
                              void* d_out, int out_size, void* d_ws, size_t ws_size,
                              hipStream_t stream)
{
  const float* x   = (const float*)d_in[0];
  const float* wq  = (const float*)d_in[1];
  const float* wk  = (const float*)d_in[2];
  const float* wg  = (const float*)d_in[3];
  const float* ape = (const float*)d_in[4];

  // ws layout (bf16): wT[3][384][768] | q[16384][384] | keys[4096][384]
  bf16* wT   = (bf16*)d_ws;
  bf16* qb   = wT + 3 * (size_t)HD_ * E_;
  bf16* keys = qb + (size_t)MT_ * HD_;

  // x_bf16 staged in d_out (dead before scores overwrite it)
  bf16* xb = (bf16*)d_out;

  cvt_x_kernel<<<dim3(MT_ * E_ / 8 / 256), dim3(256), 0, stream>>>(x, xb);
  cvt_w_t<<<dim3(E_ / 32, HD_ / 32, 3), dim3(256), 0, stream>>>(wq, wk, wg, wT);

  gemm_kg_mfma<<<dim3(MT_ / 128, HD_ / 128), dim3(256), 0, stream>>>(
      xb, wT + (size_t)HD_ * E_, wT + 2 * (size_t)HD_ * E_, ape, keys);
  gemm_q_mfma<<<dim3(MT_ / 128, HD_ / 128), dim3(256), 0, stream>>>(xb, wT, qb);

  gemm_score_mfma<<<dim3(T_ / 128, G_ / 128, B_), dim3(256), 0, stream>>>(
      qb, keys, (float*)d_out);

  topk_kernel<<<dim3(MT_ / 4), dim3(256), 0, stream>>>((float*)d_out);
  write_ends<<<dim3((G_ + 255) / 256), dim3(256), 0, stream>>>(
      (int*)d_out + (size_t)B_ * T_ * G_);
}

// Round 5
// 129.089 us; speedup vs baseline: 5.3405x; 1.2300x over previous
//
#include <hip/hip_runtime.h>
#include <hip/hip_bf16.h>
#include <math.h>

#define B_    4
#define T_    4096
#define E_    768
#define H_    6
#define D_    64
#define HD_   384
#define G_    1024
#define RATIO_ 4
#define TOPK_ 8
#define MT_   (B_*T_)   // 16384 rows total

typedef __attribute__((ext_vector_type(8))) short short8;
typedef __attribute__((ext_vector_type(4))) float f32x4;
typedef __hip_bfloat16 bf16;

// async global->LDS, 16B per lane (dest = linear tid*16; swizzle lives in the
// per-lane GLOBAL source address — rule #21: linear dest + inverse-swz source)
#define GLD16(g, l) __builtin_amdgcn_global_load_lds( \
    (const __attribute__((address_space(1))) void*)(g), \
    (__attribute__((address_space(3))) void*)(l), 16, 0, 0)

static __device__ __forceinline__ unsigned short f2bf(float f) {
  bf16 h = __float2bfloat16(f);
  return __builtin_bit_cast(unsigned short, h);
}

// ---------------------------------------------------------------------------
// x f32 -> bf16 (8 elems/thread)
// ---------------------------------------------------------------------------
__global__ __launch_bounds__(256) void cvt_x_kernel(
    const float* __restrict__ in, bf16* __restrict__ out)
{
  size_t i = (size_t)blockIdx.x * 256 + threadIdx.x;
  const float4* p = reinterpret_cast<const float4*>(in) + i * 2;
  float4 v0 = p[0], v1 = p[1];
  float f[8] = {v0.x, v0.y, v0.z, v0.w, v1.x, v1.y, v1.z, v1.w};
  union { unsigned short u[8]; short8 v; } r;
#pragma unroll
  for (int k = 0; k < 8; ++k) r.u[k] = f2bf(f[k]);
  *reinterpret_cast<short8*>(out + i * 8) = r.v;
}

// ---------------------------------------------------------------------------
// transpose+convert weights: w [768][384] f32 -> wT [384][768] bf16 (x3)
// ---------------------------------------------------------------------------
__global__ __launch_bounds__(256) void cvt_w_t(
    const float* __restrict__ wq, const float* __restrict__ wk,
    const float* __restrict__ wg, bf16* __restrict__ outbase)
{
  const float* src = blockIdx.z == 0 ? wq : (blockIdx.z == 1 ? wk : wg);
  bf16* dst = outbase + (size_t)blockIdx.z * HD_ * E_;
  __shared__ float t[32][33];
  int r = threadIdx.x >> 5, c = threadIdx.x & 31;
  int k0 = blockIdx.x * 32, n0 = blockIdx.y * 32;
#pragma unroll
  for (int i = 0; i < 4; ++i)
    t[r + i * 8][c] = src[(size_t)(k0 + r + i * 8) * HD_ + n0 + c];
  __syncthreads();
#pragma unroll
  for (int i = 0; i < 4; ++i)
    dst[(size_t)(n0 + r + i * 8) * E_ + k0 + c] = __float2bfloat16(t[c][r + i * 8]);
}

// ---------------------------------------------------------------------------
// Fused k/gate projection + gated pooling + rmsnorm -> keys bf16 [B*G][384].
// 64x128 tile, BK=32, dbuf LDS, swizzled slots. Waves 2x2, wave tile 32x64.
// ---------------------------------------------------------------------------
__global__ __launch_bounds__(256) void gemm_kg_mfma(
    const bf16* __restrict__ X, const bf16* __restrict__ WkT,
    const bf16* __restrict__ WgT, const float* __restrict__ ape,
    bf16* __restrict__ keys)
{
  // per buf (elems): A [0,2048) BK [2048,6144) BG [6144,10240)  = 20KB
  __shared__ bf16 lds[2][10240];
  const int tid = threadIdx.x;
  const int lane = tid & 63, wv = tid >> 6;
  const int wm = wv >> 1, wn = wv & 1;
  const int ll = lane & 15, lh = lane >> 4;
  const int m0 = blockIdx.x * 64, n0 = blockIdx.y * 128;
  const int srow = tid >> 2;
  const int scol = (((tid & 3) ^ ((tid >> 3) & 3)) << 3);  // swizzled source slot
  const bf16* pA  = X   + (size_t)(m0 + srow) * E_ + scol;
  const bf16* pK0 = WkT + (size_t)(n0 + srow) * E_ + scol;
  const bf16* pK1 = WkT + (size_t)(n0 + 64 + srow) * E_ + scol;
  const bf16* pG0 = WgT + (size_t)(n0 + srow) * E_ + scol;
  const bf16* pG1 = WgT + (size_t)(n0 + 64 + srow) * E_ + scol;

#define KG_STAGE(b, k0) do { \
    char* base_ = (char*)&lds[b][0] + tid * 16; \
    GLD16(pA  + (k0), base_); \
    GLD16(pK0 + (k0), base_ + 4096); \
    GLD16(pK1 + (k0), base_ + 8192); \
    GLD16(pG0 + (k0), base_ + 12288); \
    GLD16(pG1 + (k0), base_ + 16384); \
  } while (0)

  f32x4 accK[2][4], accG[2][4];
#pragma unroll
  for (int m = 0; m < 2; ++m)
#pragma unroll
    for (int n = 0; n < 4; ++n) {
      accK[m][n] = (f32x4){0.f, 0.f, 0.f, 0.f};
      accG[m][n] = (f32x4){0.f, 0.f, 0.f, 0.f};
    }
  const int asw = (lh ^ ((ll >> 1) & 3)) << 3;  // swizzled read slot (elems)

  KG_STAGE(0, 0);
  __syncthreads();
  for (int k0 = 0; k0 < E_; k0 += 32) {
    const int cur = (k0 >> 5) & 1;
    if (k0 + 32 < E_) KG_STAGE(cur ^ 1, k0 + 32);
    const bf16* Lb = &lds[cur][0];
    short8 a[2], bk[4], bg[4];
#pragma unroll
    for (int m = 0; m < 2; ++m)
      a[m] = *reinterpret_cast<const short8*>(&Lb[(wm * 32 + m * 16 + ll) * 32 + asw]);
#pragma unroll
    for (int n = 0; n < 4; ++n) {
      int R = wn * 64 + n * 16 + ll;
      bk[n] = *reinterpret_cast<const short8*>(&Lb[2048 + R * 32 + asw]);
      bg[n] = *reinterpret_cast<const short8*>(&Lb[6144 + R * 32 + asw]);
    }
#pragma unroll
    for (int m = 0; m < 2; ++m)
#pragma unroll
      for (int n = 0; n < 4; ++n) {
        accK[m][n] = __builtin_amdgcn_mfma_f32_16x16x32_bf16(a[m], bk[n], accK[m][n], 0, 0, 0);
        accG[m][n] = __builtin_amdgcn_mfma_f32_16x16x32_bf16(a[m], bg[n], accG[m][n], 0, 0, 0);
      }
    __syncthreads();
  }
#undef KG_STAGE
  float apev[4][4];
#pragma unroll
  for (int n = 0; n < 4; ++n) {
    int col = n0 + wn * 64 + n * 16 + ll;
#pragma unroll
    for (int j = 0; j < 4; ++j) apev[n][j] = ape[j * HD_ + col];
  }
#pragma unroll
  for (int m = 0; m < 2; ++m) {
    float pooled[4];
#pragma unroll
    for (int n = 0; n < 4; ++n) {
      float g0 = accG[m][n][0] + apev[n][0], g1 = accG[m][n][1] + apev[n][1];
      float g2 = accG[m][n][2] + apev[n][2], g3 = accG[m][n][3] + apev[n][3];
      float mx = fmaxf(fmaxf(g0, g1), fmaxf(g2, g3));
      float e0 = expf(g0 - mx), e1 = expf(g1 - mx);
      float e2 = expf(g2 - mx), e3 = expf(g3 - mx);
      float inv = 1.0f / (e0 + e1 + e2 + e3);
      pooled[n] = (accK[m][n][0] * e0 + accK[m][n][1] * e1 +
                   accK[m][n][2] * e2 + accK[m][n][3] * e3) * inv;
    }
    float ss = pooled[0] * pooled[0] + pooled[1] * pooled[1] +
               pooled[2] * pooled[2] + pooled[3] * pooled[3];
    ss += __shfl_xor(ss, 1, 64); ss += __shfl_xor(ss, 2, 64);
    ss += __shfl_xor(ss, 4, 64); ss += __shfl_xor(ss, 8, 64);
    float scl = rsqrtf(ss * (1.0f / D_) + 1e-6f);
    int prow = (m0 >> 2) + wm * 8 + m * 4 + lh;
#pragma unroll
    for (int n = 0; n < 4; ++n)
      keys[(size_t)prow * HD_ + n0 + wn * 64 + n * 16 + ll] =
          __float2bfloat16(pooled[n] * scl);
  }
}

// ---------------------------------------------------------------------------
// q projection + per-head rmsnorm -> q bf16 [MT][384]. 64x128 tile, dbuf+swz.
// ---------------------------------------------------------------------------
__global__ __launch_bounds__(256) void gemm_q_mfma(
    const bf16* __restrict__ X, const bf16* __restrict__ WqT,
    bf16* __restrict__ Q)
{
  __shared__ bf16 lds[2][6144];  // A [0,2048) B [2048,6144)  = 12KB/buf
  const int tid = threadIdx.x;
  const int lane = tid & 63, wv = tid >> 6;
  const int wm = wv >> 1, wn = wv & 1;
  const int ll = lane & 15, lh = lane >> 4;
  const int m0 = blockIdx.x * 64, n0 = blockIdx.y * 128;
  const int srow = tid >> 2;
  const int scol = (((tid & 3) ^ ((tid >> 3) & 3)) << 3);
  const bf16* pA  = X   + (size_t)(m0 + srow) * E_ + scol;
  const bf16* pB0 = WqT + (size_t)(n0 + srow) * E_ + scol;
  const bf16* pB1 = WqT + (size_t)(n0 + 64 + srow) * E_ + scol;

#define Q_STAGE(b, k0) do { \
    char* base_ = (char*)&lds[b][0] + tid * 16; \
    GLD16(pA  + (k0), base_); \
    GLD16(pB0 + (k0), base_ + 4096); \
    GLD16(pB1 + (k0), base_ + 8192); \
  } while (0)

  f32x4 acc[2][4];
#pragma unroll
  for (int m = 0; m < 2; ++m)
#pragma unroll
    for (int n = 0; n < 4; ++n) acc[m][n] = (f32x4){0.f, 0.f, 0.f, 0.f};
  const int asw = (lh ^ ((ll >> 1) & 3)) << 3;

  Q_STAGE(0, 0);
  __syncthreads();
  for (int k0 = 0; k0 < E_; k0 += 32) {
    const int cur = (k0 >> 5) & 1;
    if (k0 + 32 < E_) Q_STAGE(cur ^ 1, k0 + 32);
    const bf16* Lb = &lds[cur][0];
    short8 a[2], b[4];
#pragma unroll
    for (int m = 0; m < 2; ++m)
      a[m] = *reinterpret_cast<const short8*>(&Lb[(wm * 32 + m * 16 + ll) * 32 + asw]);
#pragma unroll
    for (int n = 0; n < 4; ++n)
      b[n] = *reinterpret_cast<const short8*>(&Lb[2048 + (wn * 64 + n * 16 + ll) * 32 + asw]);
#pragma unroll
    for (int m = 0; m < 2; ++m)
#pragma unroll
      for (int n = 0; n < 4; ++n)
        acc[m][n] = __builtin_amdgcn_mfma_f32_16x16x32_bf16(a[m], b[n], acc[m][n], 0, 0, 0);
    __syncthreads();
  }
#undef Q_STAGE
#pragma unroll
  for (int m = 0; m < 2; ++m)
#pragma unroll
    for (int j = 0; j < 4; ++j) {
      float ss = 0.f;
#pragma unroll
      for (int n = 0; n < 4; ++n) ss += acc[m][n][j] * acc[m][n][j];
      ss += __shfl_xor(ss, 1, 64); ss += __shfl_xor(ss, 2, 64);
      ss += __shfl_xor(ss, 4, 64); ss += __shfl_xor(ss, 8, 64);
      float scl = rsqrtf(ss * (1.0f / D_) + 1e-6f);
      int row = m0 + wm * 32 + m * 16 + lh * 4 + j;
#pragma unroll
      for (int n = 0; n < 4; ++n)
        Q[(size_t)row * HD_ + n0 + wn * 64 + n * 16 + ll] =
            __float2bfloat16(acc[m][n][j] * scl);
    }
}

// ---------------------------------------------------------------------------
// Batched score GEMM: scores[z] = q[z] @ keys[z]^T * (D^-0.5/H). 64x128 tile,
// dbuf+swz, causal dead-tile skip.
// ---------------------------------------------------------------------------
__global__ __launch_bounds__(256) void gemm_score_mfma(
    const bf16* __restrict__ Qall, const bf16* __restrict__ Kall,
    float* __restrict__ Call)
{
  const int m0 = blockIdx.x * 64, n0 = blockIdx.y * 128;
  if (4 * n0 >= m0 + 64) return;   // all cols >= gmax for every row in tile
  __shared__ bf16 lds[2][6144];
  const bf16* Qb = Qall + (size_t)blockIdx.z * T_ * HD_;
  const bf16* Kb = Kall + (size_t)blockIdx.z * G_ * HD_;
  float* C = Call + (size_t)blockIdx.z * T_ * G_;
  const int tid = threadIdx.x;
  const int lane = tid & 63, wv = tid >> 6;
  const int wm = wv >> 1, wn = wv & 1;
  const int ll = lane & 15, lh = lane >> 4;
  const int srow = tid >> 2;
  const int scol = (((tid & 3) ^ ((tid >> 3) & 3)) << 3);
  const bf16* pA  = Qb + (size_t)(m0 + srow) * HD_ + scol;
  const bf16* pB0 = Kb + (size_t)(n0 + srow) * HD_ + scol;
  const bf16* pB1 = Kb + (size_t)(n0 + 64 + srow) * HD_ + scol;

#define S_STAGE(b, k0) do { \
    char* base_ = (char*)&lds[b][0] + tid * 16; \
    GLD16(pA  + (k0), base_); \
    GLD16(pB0 + (k0), base_ + 4096); \
    GLD16(pB1 + (k0), base_ + 8192); \
  } while (0)

  f32x4 acc[2][4];
#pragma unroll
  for (int m = 0; m < 2; ++m)
#pragma unroll
    for (int n = 0; n < 4; ++n) acc[m][n] = (f32x4){0.f, 0.f, 0.f, 0.f};
  const int asw = (lh ^ ((ll >> 1) & 3)) << 3;

  S_STAGE(0, 0);
  __syncthreads();
  for (int k0 = 0; k0 < HD_; k0 += 32) {
    const int cur = (k0 >> 5) & 1;
    if (k0 + 32 < HD_) S_STAGE(cur ^ 1, k0 + 32);
    const bf16* Lb = &lds[cur][0];
    short8 a[2], b[4];
#pragma unroll
    for (int m = 0; m < 2; ++m)
      a[m] = *reinterpret_cast<const short8*>(&Lb[(wm * 32 + m * 16 + ll) * 32 + asw]);
#pragma unroll
    for (int n = 0; n < 4; ++n)
      b[n] = *reinterpret_cast<const short8*>(&Lb[2048 + (wn * 64 + n * 16 + ll) * 32 + asw]);
#pragma unroll
    for (int m = 0; m < 2; ++m)
#pragma unroll
      for (int n = 0; n < 4; ++n)
        acc[m][n] = __builtin_amdgcn_mfma_f32_16x16x32_bf16(a[m], b[n], acc[m][n], 0, 0, 0);
    __syncthreads();
  }
#undef S_STAGE
  const float scale = 0.125f / 6.0f;
#pragma unroll
  for (int m = 0; m < 2; ++m)
#pragma unroll
    for (int j = 0; j < 4; ++j) {
      int row = m0 + wm * 32 + m * 16 + lh * 4 + j;
#pragma unroll
      for (int n = 0; n < 4; ++n)
        C[(size_t)row * G_ + n0 + wn * 64 + n * 16 + ll] = acc[m][n][j] * scale;
    }
}

// ---------------------------------------------------------------------------
// Wave-per-row causal top-8: registers only, no LDS, no barriers.
// ---------------------------------------------------------------------------
__global__ __launch_bounds__(256) void topk_kernel(float* __restrict__ scores)
{
  const int r = blockIdx.x * 4 + (threadIdx.x >> 6);
  const int lane = threadIdx.x & 63;
  const int t = r & (T_ - 1);
  const int gmax = (t + 1) >> 2;
  float* row = scores + (size_t)r * G_;
  const int base = lane << 4;
  const float4* p = reinterpret_cast<const float4*>(row + base);
  float4 x0 = p[0], x1 = p[1], x2 = p[2], x3 = p[3];
  float v[16] = {x0.x, x0.y, x0.z, x0.w, x1.x, x1.y, x1.z, x1.w,
                 x2.x, x2.y, x2.z, x2.w, x3.x, x3.y, x3.z, x3.w};
#pragma unroll
  for (int j = 0; j < 16; ++j)
    if (base + j >= gmax) v[j] = -INFINITY;
  float lv = v[0]; int li = 0;
#pragma unroll
  for (int j = 1; j < 16; ++j)
    if (v[j] > lv) { lv = v[j]; li = j; }
  unsigned sel = 0;
  const int nsel = gmax < TOPK_ ? gmax : TOPK_;
  for (int it = 0; it < nsel; ++it) {
    float bv = lv; int bi = base + li;
#pragma unroll
    for (int off = 1; off < 64; off <<= 1) {
      float ov = __shfl_xor(bv, off, 64);
      int oi = __shfl_xor(bi, off, 64);
      if (ov > bv || (ov == bv && oi < bi)) { bv = ov; bi = oi; }
    }
    if ((bi >> 4) == lane) {          // winner lane only
      sel |= 1u << (bi & 15);
      v[bi & 15] = -INFINITY;
      lv = v[0]; li = 0;
#pragma unroll
      for (int j = 1; j < 16; ++j)
        if (v[j] > lv) { lv = v[j]; li = j; }
    }
  }
  int4* q = reinterpret_cast<int4*>(row + base);
#pragma unroll
  for (int c = 0; c < 4; ++c)
    q[c] = make_int4((sel >> (4 * c)) & 1, (sel >> (4 * c + 1)) & 1,
                     (sel >> (4 * c + 2)) & 1, (sel >> (4 * c + 3)) & 1);
}

__global__ __launch_bounds__(256) void write_ends(int* __restrict__ out)
{
  int g = blockIdx.x * 256 + threadIdx.x;
  if (g < G_) {
    int e = g * RATIO_ + RATIO_ - 1;
    out[g] = (e < T_ - 1 ? e : T_ - 1);
  }
}

extern "C" void kernel_launch(void* const* d_in, const int* in_sizes, int n_in,
                              void* d_out, int out_size, void* d_ws, size_t ws_size,
                              hipStream_t stream)
{
  const float* x   = (const float*)d_in[0];
  const float* wq  = (const float*)d_in[1];
  const float* wk  = (const float*)d_in[2];
  const float* wg  = (const float*)d_in[3];
  const float* ape = (const float*)d_in[4];

  // ws layout (bf16): wT[3][384][768] | q[16384][384] | keys[4096][384]
  bf16* wT   = (bf16*)d_ws;
  bf16* qb   = wT + 3 * (size_t)HD_ * E_;
  bf16* keys = qb + (size_t)MT_ * HD_;

  // x_bf16 staged in d_out (dead before scores overwrite it)
  bf16* xb = (bf16*)d_out;

  cvt_x_kernel<<<dim3(MT_ * E_ / 8 / 256), dim3(256), 0, stream>>>(x, xb);
  cvt_w_t<<<dim3(E_ / 32, HD_ / 32, 3), dim3(256), 0, stream>>>(wq, wk, wg, wT);

  gemm_kg_mfma<<<dim3(MT_ / 64, HD_ / 128), dim3(256), 0, stream>>>(
      xb, wT + (size_t)HD_ * E_, wT + 2 * (size_t)HD_ * E_, ape, keys);
  gemm_q_mfma<<<dim3(MT_ / 64, HD_ / 128), dim3(256), 0, stream>>>(xb, wT, qb);

  gemm_score_mfma<<<dim3(T_ / 64, G_ / 128, B_), dim3(256), 0, stream>>>(
      qb, keys, (float*)d_out);

  topk_kernel<<<dim3(MT_ / 4), dim3(256), 0, stream>>>((float*)d_out);
  write_ends<<<dim3((G_ + 255) / 256), dim3(256), 0, stream>>>(
      (int*)d_out + (size_t)B_ * T_ * G_);
}

// Round 6
// 127.564 us; speedup vs baseline: 5.4043x; 1.0120x over previous
//
#include <hip/hip_runtime.h>
#include <hip/hip_bf16.h>
#include <math.h>

#define B_    4
#define T_    4096
#define E_    768
#define H_    6
#define D_    64
#define HD_   384
#define G_    1024
#define RATIO_ 4
#define TOPK_ 8
#define MT_   (B_*T_)   // 16384 rows total

typedef __attribute__((ext_vector_type(8))) short short8;
typedef __attribute__((ext_vector_type(4))) float f32x4;
typedef __hip_bfloat16 bf16;

// async global->LDS, 16B per lane (dest = linear tid*16; swizzle lives in the
// per-lane GLOBAL source address — rule #21: linear dest + inverse-swz source)
#define GLD16(g, l) __builtin_amdgcn_global_load_lds( \
    (const __attribute__((address_space(1))) void*)(g), \
    (__attribute__((address_space(3))) void*)(l), 16, 0, 0)

static __device__ __forceinline__ unsigned short f2bf(float f) {
  bf16 h = __float2bfloat16(f);
  return __builtin_bit_cast(unsigned short, h);
}

// ---------------------------------------------------------------------------
// x f32 -> bf16 (8 elems/thread)
// ---------------------------------------------------------------------------
__global__ __launch_bounds__(256) void cvt_x_kernel(
    const float* __restrict__ in, bf16* __restrict__ out)
{
  size_t i = (size_t)blockIdx.x * 256 + threadIdx.x;
  const float4* p = reinterpret_cast<const float4*>(in) + i * 2;
  float4 v0 = p[0], v1 = p[1];
  float f[8] = {v0.x, v0.y, v0.z, v0.w, v1.x, v1.y, v1.z, v1.w};
  union { unsigned short u[8]; short8 v; } r;
#pragma unroll
  for (int k = 0; k < 8; ++k) r.u[k] = f2bf(f[k]);
  *reinterpret_cast<short8*>(out + i * 8) = r.v;
}

// ---------------------------------------------------------------------------
// transpose+convert weights: w [768][384] f32 -> wT [384][768] bf16 (x3)
// ---------------------------------------------------------------------------
__global__ __launch_bounds__(256) void cvt_w_t(
    const float* __restrict__ wq, const float* __restrict__ wk,
    const float* __restrict__ wg, bf16* __restrict__ outbase)
{
  const float* src = blockIdx.z == 0 ? wq : (blockIdx.z == 1 ? wk : wg);
  bf16* dst = outbase + (size_t)blockIdx.z * HD_ * E_;
  __shared__ float t[32][33];
  int r = threadIdx.x >> 5, c = threadIdx.x & 31;
  int k0 = blockIdx.x * 32, n0 = blockIdx.y * 32;
#pragma unroll
  for (int i = 0; i < 4; ++i)
    t[r + i * 8][c] = src[(size_t)(k0 + r + i * 8) * HD_ + n0 + c];
  __syncthreads();
#pragma unroll
  for (int i = 0; i < 4; ++i)
    dst[(size_t)(n0 + r + i * 8) * E_ + k0 + c] = __float2bfloat16(t[c][r + i * 8]);
}

// ---------------------------------------------------------------------------
// Fused q/k/gate projection: one pass over x-tiles produces BOTH
//   q (rmsnormed, bf16 [MT][384]) and keys (pooled+rmsnormed bf16 [B*G][384]).
// 64x128 tile, BK=32, dbuf LDS (56KB), swizzled slots. Waves 2x2.
// ---------------------------------------------------------------------------
__global__ __launch_bounds__(256) void gemm_qkg_mfma(
    const bf16* __restrict__ X, const bf16* __restrict__ WqT,
    const bf16* __restrict__ WkT, const bf16* __restrict__ WgT,
    const float* __restrict__ ape, bf16* __restrict__ Q,
    bf16* __restrict__ keys)
{
  // per buf (elems): A[0,2048) Q0[2048) Q1[4096) K0[6144) K1[8192)
  //                  G0[10240) G1[12288)   total 14336 elems = 28KB
  __shared__ bf16 lds[2][14336];
  const int tid = threadIdx.x;
  const int lane = tid & 63, wv = tid >> 6;
  const int wm = wv >> 1, wn = wv & 1;
  const int ll = lane & 15, lh = lane >> 4;
  const int m0 = blockIdx.x * 64, n0 = blockIdx.y * 128;
  const int srow = tid >> 2;
  const int scol = (((tid & 3) ^ ((tid >> 3) & 3)) << 3);  // swizzled source slot
  const bf16* pA  = X   + (size_t)(m0 + srow) * E_ + scol;
  const bf16* pQ0 = WqT + (size_t)(n0 + srow) * E_ + scol;
  const bf16* pQ1 = WqT + (size_t)(n0 + 64 + srow) * E_ + scol;
  const bf16* pK0 = WkT + (size_t)(n0 + srow) * E_ + scol;
  const bf16* pK1 = WkT + (size_t)(n0 + 64 + srow) * E_ + scol;
  const bf16* pG0 = WgT + (size_t)(n0 + srow) * E_ + scol;
  const bf16* pG1 = WgT + (size_t)(n0 + 64 + srow) * E_ + scol;

#define QKG_STAGE(b, k0) do { \
    char* base_ = (char*)&lds[b][0] + tid * 16; \
    GLD16(pA  + (k0), base_); \
    GLD16(pQ0 + (k0), base_ + 4096); \
    GLD16(pQ1 + (k0), base_ + 8192); \
    GLD16(pK0 + (k0), base_ + 12288); \
    GLD16(pK1 + (k0), base_ + 16384); \
    GLD16(pG0 + (k0), base_ + 20480); \
    GLD16(pG1 + (k0), base_ + 24576); \
  } while (0)

  f32x4 accQ[2][4], accK[2][4], accG[2][4];
#pragma unroll
  for (int m = 0; m < 2; ++m)
#pragma unroll
    for (int n = 0; n < 4; ++n) {
      accQ[m][n] = (f32x4){0.f, 0.f, 0.f, 0.f};
      accK[m][n] = (f32x4){0.f, 0.f, 0.f, 0.f};
      accG[m][n] = (f32x4){0.f, 0.f, 0.f, 0.f};
    }
  const int asw = (lh ^ ((ll >> 1) & 3)) << 3;  // swizzled read slot (elems)

  QKG_STAGE(0, 0);
  __syncthreads();
  for (int k0 = 0; k0 < E_; k0 += 32) {
    const int cur = (k0 >> 5) & 1;
    if (k0 + 32 < E_) QKG_STAGE(cur ^ 1, k0 + 32);
    const bf16* Lb = &lds[cur][0];
    short8 a[2], bq[4], bk[4], bg[4];
#pragma unroll
    for (int m = 0; m < 2; ++m)
      a[m] = *reinterpret_cast<const short8*>(&Lb[(wm * 32 + m * 16 + ll) * 32 + asw]);
#pragma unroll
    for (int n = 0; n < 4; ++n) {
      int R = (wn * 64 + n * 16 + ll) * 32 + asw;
      bq[n] = *reinterpret_cast<const short8*>(&Lb[2048 + R]);
      bk[n] = *reinterpret_cast<const short8*>(&Lb[6144 + R]);
      bg[n] = *reinterpret_cast<const short8*>(&Lb[10240 + R]);
    }
#pragma unroll
    for (int m = 0; m < 2; ++m)
#pragma unroll
      for (int n = 0; n < 4; ++n) {
        accQ[m][n] = __builtin_amdgcn_mfma_f32_16x16x32_bf16(a[m], bq[n], accQ[m][n], 0, 0, 0);
        accK[m][n] = __builtin_amdgcn_mfma_f32_16x16x32_bf16(a[m], bk[n], accK[m][n], 0, 0, 0);
        accG[m][n] = __builtin_amdgcn_mfma_f32_16x16x32_bf16(a[m], bg[n], accG[m][n], 0, 0, 0);
      }
    __syncthreads();
  }
#undef QKG_STAGE

  // ---- q epilogue: per-(row,head) rmsnorm (wave's 64 cols == one head) ----
#pragma unroll
  for (int m = 0; m < 2; ++m)
#pragma unroll
    for (int j = 0; j < 4; ++j) {
      float ss = 0.f;
#pragma unroll
      for (int n = 0; n < 4; ++n) ss += accQ[m][n][j] * accQ[m][n][j];
      ss += __shfl_xor(ss, 1, 64); ss += __shfl_xor(ss, 2, 64);
      ss += __shfl_xor(ss, 4, 64); ss += __shfl_xor(ss, 8, 64);
      float scl = rsqrtf(ss * (1.0f / D_) + 1e-6f);
      int row = m0 + wm * 32 + m * 16 + lh * 4 + j;
#pragma unroll
      for (int n = 0; n < 4; ++n)
        Q[(size_t)row * HD_ + n0 + wn * 64 + n * 16 + ll] =
            __float2bfloat16(accQ[m][n][j] * scl);
    }

  // ---- keys epilogue: lane-local softmax over 4 group rows + rmsnorm ----
  float apev[4][4];
#pragma unroll
  for (int n = 0; n < 4; ++n) {
    int col = n0 + wn * 64 + n * 16 + ll;
#pragma unroll
    for (int j = 0; j < 4; ++j) apev[n][j] = ape[j * HD_ + col];
  }
#pragma unroll
  for (int m = 0; m < 2; ++m) {
    float pooled[4];
#pragma unroll
    for (int n = 0; n < 4; ++n) {
      float g0 = accG[m][n][0] + apev[n][0], g1 = accG[m][n][1] + apev[n][1];
      float g2 = accG[m][n][2] + apev[n][2], g3 = accG[m][n][3] + apev[n][3];
      float mx = fmaxf(fmaxf(g0, g1), fmaxf(g2, g3));
      float e0 = expf(g0 - mx), e1 = expf(g1 - mx);
      float e2 = expf(g2 - mx), e3 = expf(g3 - mx);
      float inv = 1.0f / (e0 + e1 + e2 + e3);
      pooled[n] = (accK[m][n][0] * e0 + accK[m][n][1] * e1 +
                   accK[m][n][2] * e2 + accK[m][n][3] * e3) * inv;
    }
    float ss = pooled[0] * pooled[0] + pooled[1] * pooled[1] +
               pooled[2] * pooled[2] + pooled[3] * pooled[3];
    ss += __shfl_xor(ss, 1, 64); ss += __shfl_xor(ss, 2, 64);
    ss += __shfl_xor(ss, 4, 64); ss += __shfl_xor(ss, 8, 64);
    float scl = rsqrtf(ss * (1.0f / D_) + 1e-6f);
    int prow = (m0 >> 2) + wm * 8 + m * 4 + lh;
#pragma unroll
    for (int n = 0; n < 4; ++n)
      keys[(size_t)prow * HD_ + n0 + wn * 64 + n * 16 + ll] =
          __float2bfloat16(pooled[n] * scl);
  }
}

// ---------------------------------------------------------------------------
// Batched score GEMM: scores[z] = q[z] @ keys[z]^T * (D^-0.5/H). 64x128 tile,
// dbuf+swz, causal dead-tile skip.
// ---------------------------------------------------------------------------
__global__ __launch_bounds__(256) void gemm_score_mfma(
    const bf16* __restrict__ Qall, const bf16* __restrict__ Kall,
    float* __restrict__ Call)
{
  const int m0 = blockIdx.x * 64, n0 = blockIdx.y * 128;
  if (4 * n0 >= m0 + 64) return;   // all cols >= gmax for every row in tile
  __shared__ bf16 lds[2][6144];
  const bf16* Qb = Qall + (size_t)blockIdx.z * T_ * HD_;
  const bf16* Kb = Kall + (size_t)blockIdx.z * G_ * HD_;
  float* C = Call + (size_t)blockIdx.z * T_ * G_;
  const int tid = threadIdx.x;
  const int lane = tid & 63, wv = tid >> 6;
  const int wm = wv >> 1, wn = wv & 1;
  const int ll = lane & 15, lh = lane >> 4;
  const int srow = tid >> 2;
  const int scol = (((tid & 3) ^ ((tid >> 3) & 3)) << 3);
  const bf16* pA  = Qb + (size_t)(m0 + srow) * HD_ + scol;
  const bf16* pB0 = Kb + (size_t)(n0 + srow) * HD_ + scol;
  const bf16* pB1 = Kb + (size_t)(n0 + 64 + srow) * HD_ + scol;

#define S_STAGE(b, k0) do { \
    char* base_ = (char*)&lds[b][0] + tid * 16; \
    GLD16(pA  + (k0), base_); \
    GLD16(pB0 + (k0), base_ + 4096); \
    GLD16(pB1 + (k0), base_ + 8192); \
  } while (0)

  f32x4 acc[2][4];
#pragma unroll
  for (int m = 0; m < 2; ++m)
#pragma unroll
    for (int n = 0; n < 4; ++n) acc[m][n] = (f32x4){0.f, 0.f, 0.f, 0.f};
  const int asw = (lh ^ ((ll >> 1) & 3)) << 3;

  S_STAGE(0, 0);
  __syncthreads();
  for (int k0 = 0; k0 < HD_; k0 += 32) {
    const int cur = (k0 >> 5) & 1;
    if (k0 + 32 < HD_) S_STAGE(cur ^ 1, k0 + 32);
    const bf16* Lb = &lds[cur][0];
    short8 a[2], b[4];
#pragma unroll
    for (int m = 0; m < 2; ++m)
      a[m] = *reinterpret_cast<const short8*>(&Lb[(wm * 32 + m * 16 + ll) * 32 + asw]);
#pragma unroll
    for (int n = 0; n < 4; ++n)
      b[n] = *reinterpret_cast<const short8*>(&Lb[2048 + (wn * 64 + n * 16 + ll) * 32 + asw]);
#pragma unroll
    for (int m = 0; m < 2; ++m)
#pragma unroll
      for (int n = 0; n < 4; ++n)
        acc[m][n] = __builtin_amdgcn_mfma_f32_16x16x32_bf16(a[m], b[n], acc[m][n], 0, 0, 0);
    __syncthreads();
  }
#undef S_STAGE
  const float scale = 0.125f / 6.0f;
#pragma unroll
  for (int m = 0; m < 2; ++m)
#pragma unroll
    for (int j = 0; j < 4; ++j) {
      int row = m0 + wm * 32 + m * 16 + lh * 4 + j;
#pragma unroll
      for (int n = 0; n < 4; ++n)
        C[(size_t)row * G_ + n0 + wn * 64 + n * 16 + ll] = acc[m][n][j] * scale;
    }
}

// ---------------------------------------------------------------------------
// Wave-per-row causal top-8: registers only, no LDS, no barriers.
// Causal load predication: never touch the (cold, garbage) non-causal region.
// Block 0 also writes group_ends.
// ---------------------------------------------------------------------------
__global__ __launch_bounds__(256) void topk_kernel(float* __restrict__ scores,
                                                   int* __restrict__ ends)
{
  if (blockIdx.x == 0) {
    int g = threadIdx.x;
#pragma unroll
    for (int c = 0; c < 4; ++c, g += 256) {
      int e = g * RATIO_ + RATIO_ - 1;
      ends[g] = (e < T_ - 1 ? e : T_ - 1);
    }
  }
  const int r = blockIdx.x * 4 + (threadIdx.x >> 6);
  const int lane = threadIdx.x & 63;
  const int t = r & (T_ - 1);
  const int gmax = (t + 1) >> 2;
  float* row = scores + (size_t)r * G_;
  const int base = lane << 4;
  const float4* p = reinterpret_cast<const float4*>(row + base);
  float4 xv[4];
#pragma unroll
  for (int c = 0; c < 4; ++c) {
    if (base + 4 * c < gmax) xv[c] = p[c];
    else xv[c] = make_float4(-INFINITY, -INFINITY, -INFINITY, -INFINITY);
  }
  float v[16] = {xv[0].x, xv[0].y, xv[0].z, xv[0].w,
                 xv[1].x, xv[1].y, xv[1].z, xv[1].w,
                 xv[2].x, xv[2].y, xv[2].z, xv[2].w,
                 xv[3].x, xv[3].y, xv[3].z, xv[3].w};
#pragma unroll
  for (int j = 0; j < 16; ++j)
    if (base + j >= gmax) v[j] = -INFINITY;
  float lv = v[0]; int li = 0;
#pragma unroll
  for (int j = 1; j < 16; ++j)
    if (v[j] > lv) { lv = v[j]; li = j; }
  unsigned sel = 0;
  const int nsel = gmax < TOPK_ ? gmax : TOPK_;
  for (int it = 0; it < nsel; ++it) {
    float bv = lv; int bi = base + li;
#pragma unroll
    for (int off = 1; off < 64; off <<= 1) {
      float ov = __shfl_xor(bv, off, 64);
      int oi = __shfl_xor(bi, off, 64);
      if (ov > bv || (ov == bv && oi < bi)) { bv = ov; bi = oi; }
    }
    if ((bi >> 4) == lane) {          // winner lane only
      sel |= 1u << (bi & 15);
      v[bi & 15] = -INFINITY;
      lv = v[0]; li = 0;
#pragma unroll
      for (int j = 1; j < 16; ++j)
        if (v[j] > lv) { lv = v[j]; li = j; }
    }
  }
  int4* q = reinterpret_cast<int4*>(row + base);
#pragma unroll
  for (int c = 0; c < 4; ++c)
    q[c] = make_int4((sel >> (4 * c)) & 1, (sel >> (4 * c + 1)) & 1,
                     (sel >> (4 * c + 2)) & 1, (sel >> (4 * c + 3)) & 1);
}

extern "C" void kernel_launch(void* const* d_in, const int* in_sizes, int n_in,
                              void* d_out, int out_size, void* d_ws, size_t ws_size,
                              hipStream_t stream)
{
  const float* x   = (const float*)d_in[0];
  const float* wq  = (const float*)d_in[1];
  const float* wk  = (const float*)d_in[2];
  const float* wg  = (const float*)d_in[3];
  const float* ape = (const float*)d_in[4];

  // ws layout (bf16): wT[3][384][768] | q[16384][384] | keys[4096][384]
  bf16* wT   = (bf16*)d_ws;
  bf16* qb   = wT + 3 * (size_t)HD_ * E_;
  bf16* keys = qb + (size_t)MT_ * HD_;

  // x_bf16 staged in d_out (dead before scores overwrite it)
  bf16* xb = (bf16*)d_out;

  cvt_x_kernel<<<dim3(MT_ * E_ / 8 / 256), dim3(256), 0, stream>>>(x, xb);
  cvt_w_t<<<dim3(E_ / 32, HD_ / 32, 3), dim3(256), 0, stream>>>(wq, wk, wg, wT);

  gemm_qkg_mfma<<<dim3(MT_ / 64, HD_ / 128), dim3(256), 0, stream>>>(
      xb, wT, wT + (size_t)HD_ * E_, wT + 2 * (size_t)HD_ * E_, ape, qb, keys);

  gemm_score_mfma<<<dim3(T_ / 64, G_ / 128, B_), dim3(256), 0, stream>>>(
      qb, keys, (float*)d_out);

  topk_kernel<<<dim3(MT_ / 4), dim3(256), 0, stream>>>(
      (float*)d_out, (int*)d_out + (size_t)B_ * T_ * G_);
}